// Round 9
// baseline (414.707 us; speedup 1.0000x reference)
//
#include <hip/hip_runtime.h>
#include <math.h>

#define B_GRAPHS 16384
#define N_NODES  524288
#define E_EDGES  1048576
#define D_EMB    128
#define D_STATE  64
#define HID      32
#define PADK     136     // bf16 elems/row -> 272B row stride (16B aligned)
#define WPB      4       // waves per block; each wave owns one 32-node window
#define NWIN     (N_NODES / 32)

typedef __attribute__((ext_vector_type(8))) short short8;
typedef __attribute__((ext_vector_type(4))) float f32x4;

__device__ __forceinline__ unsigned short f2bf(float f) {
    unsigned int u = __builtin_bit_cast(unsigned int, f);
    u += 0x7fffu + ((u >> 16) & 1u);
    return (unsigned short)(u >> 16);
}
__device__ __forceinline__ float bf2f(unsigned short s) {
    unsigned int u = ((unsigned int)s) << 16;
    return __builtin_bit_cast(float, u);
}

// ---------- K1: segment offsets (batch sorted) ----------
__global__ __launch_bounds__(256) void offs_kernel(
    const int* __restrict__ batch, int* __restrict__ offs)
{
    int i = blockIdx.x * 256 + threadIdx.x;
    if (i >= N_NODES) return;
    int b = batch[i];
    int prev = (i == 0) ? -1 : batch[i - 1];
    for (int x = prev + 1; x <= b; ++x) offs[x] = i;
    if (i == N_NODES - 1)
        for (int x = b + 1; x <= B_GRAPHS; ++x) offs[x] = N_NODES;
}

// ---------- K2: hb[g][j] = b1[j] + state_emb[state[g]] @ W1[128:192,:] ----------
__global__ __launch_bounds__(256) void hb_kernel(
    const float* __restrict__ state_emb, const float* __restrict__ W1,
    const float* __restrict__ b1, const int* __restrict__ state,
    float* __restrict__ hb)
{
    int t = threadIdx.x;
    int j = t & 31;
    int g = blockIdx.x * 8 + (t >> 5);
    int st = state[g];
    const float* zs = state_emb + st * D_STATE;
    float acc = b1[j];
    #pragma unroll 8
    for (int k = 0; k < D_STATE; ++k)
        acc += zs[k] * W1[(D_EMB + k) * HID + j];
    hb[g * HID + j] = acc;
}

// ---------- K3: window kernel: logits + exp + segment pooling, NO atomics ----------
__global__ __launch_bounds__(256, 3) void window_kernel(
    const float* __restrict__ z_atom,
    const float* __restrict__ W1,
    const float* __restrict__ W2,
    const float* __restrict__ b2,
    const int*   __restrict__ batch,
    const float* __restrict__ hb,
    float*       __restrict__ out_x,
    float*       __restrict__ Sbuf,
    float*       __restrict__ rec_u,   // [NWIN*2][128]
    float*       __restrict__ rec_s,   // [NWIN*2]
    int*         __restrict__ rec_id)  // [NWIN*2]
{
    __shared__ unsigned short s_w1t[HID][PADK];     // W1[0:128,:]^T bf16 [j][k]
    __shared__ unsigned short s_zb[WPB][32][PADK];  // per-wave z window bf16 [n][k]

    const int t    = threadIdx.x;
    const int lane = t & 63;
    const int w    = t >> 6;
    const int l15  = lane & 15;
    const int kc   = lane >> 4;        // 0..3

    for (int i = t; i < D_EMB * HID; i += 256) {
        int k = i >> 5, j = i & 31;
        s_w1t[j][k] = f2bf(W1[i]);
    }
    __syncthreads();

    const float b2v = b2[0];
    float w2v[2][4];
    #pragma unroll
    for (int jh = 0; jh < 2; ++jh)
        #pragma unroll
        for (int r = 0; r < 4; ++r)
            w2v[jh][r] = W2[16 * jh + 4 * kc + r];

    unsigned short (*zb)[PADK] = s_zb[w];

    const int win = blockIdx.x * WPB + w;
    const int c0  = win * 32;
    int bv = 0;
    if (lane < 32) bv = batch[c0 + lane];

    const int leftN  = (c0 > 0) ? batch[c0 - 1] : -2;
    const int rightN = (c0 + 32 < N_NODES) ? batch[c0 + 32] : -2;

    float4 hbf[2][2];
    #pragma unroll
    for (int nh = 0; nh < 2; ++nh) {
        int bn = __shfl(bv, l15 + 16 * nh);
        hbf[nh][0] = *(const float4*)&hb[(size_t)bn * HID + 4 * kc];
        hbf[nh][1] = *(const float4*)&hb[(size_t)bn * HID + 16 + 4 * kc];
    }

    const float4* za4 = (const float4*)z_atom + (size_t)c0 * (D_EMB / 4);
    #pragma unroll
    for (int half = 0; half < 2; ++half) {
        float4 tmp[8];
        #pragma unroll
        for (int it = 0; it < 8; ++it) {
            int idx = (half * 8 + it) * 64 + lane;
            int n = idx >> 5, c = idx & 31;
            tmp[it] = za4[n * (D_EMB / 4) + c];
        }
        #pragma unroll
        for (int it = 0; it < 8; ++it) {
            int idx = (half * 8 + it) * 64 + lane;
            int n = idx >> 5, c = idx & 31;
            float4 v = tmp[it];
            unsigned lo = (unsigned)f2bf(v.x) | ((unsigned)f2bf(v.y) << 16);
            unsigned hi = (unsigned)f2bf(v.z) | ((unsigned)f2bf(v.w) << 16);
            *(uint2*)&zb[n][c * 4] = make_uint2(lo, hi);
        }
    }

    f32x4 acc[2][2] = {{{0.f,0.f,0.f,0.f},{0.f,0.f,0.f,0.f}},
                       {{0.f,0.f,0.f,0.f},{0.f,0.f,0.f,0.f}}};
    #pragma unroll
    for (int kb = 0; kb < 4; ++kb) {
        short8 a0 = *(const short8*)&s_w1t[l15][kb * 32 + kc * 8];
        short8 a1 = *(const short8*)&s_w1t[16 + l15][kb * 32 + kc * 8];
        short8 q0 = *(const short8*)&zb[l15][kb * 32 + kc * 8];
        short8 q1 = *(const short8*)&zb[16 + l15][kb * 32 + kc * 8];
        acc[0][0] = __builtin_amdgcn_mfma_f32_16x16x32_bf16(a0, q0, acc[0][0], 0, 0, 0);
        acc[1][0] = __builtin_amdgcn_mfma_f32_16x16x32_bf16(a1, q0, acc[1][0], 0, 0, 0);
        acc[0][1] = __builtin_amdgcn_mfma_f32_16x16x32_bf16(a0, q1, acc[0][1], 0, 0, 0);
        acc[1][1] = __builtin_amdgcn_mfma_f32_16x16x32_bf16(a1, q1, acc[1][1], 0, 0, 0);
    }

    float pt[2];
    #pragma unroll
    for (int nh = 0; nh < 2; ++nh) {
        float part = 0.f;
        #pragma unroll
        for (int r = 0; r < 4; ++r) {
            float h = acc[0][nh][r] + (&hbf[nh][0].x)[r];
            h = h > 0.f ? h : 0.01f * h;
            part += h * w2v[0][r];
        }
        #pragma unroll
        for (int r = 0; r < 4; ++r) {
            float h = acc[1][nh][r] + (&hbf[nh][1].x)[r];
            h = h > 0.f ? h : 0.01f * h;
            part += h * w2v[1][r];
        }
        part += __shfl_xor(part, 16);
        part += __shfl_xor(part, 32);
        pt[nh] = __expf(part + b2v);
    }

    float u0 = 0.f, u1 = 0.f, ss = 0.f;
    int cur = __shfl(bv, 0);
    int a = 0;
    bool usedL = false, usedR = false;

    #pragma unroll 4
    for (int n = 0; n < 32; ++n) {
        int bn = __shfl(bv, n);
        if (bn != cur) {
            if (a == 0 && leftN == cur) {
                *(float2*)&rec_u[(size_t)(2 * win) * 128 + lane * 2] = make_float2(u0, u1);
                if (lane == 0) { rec_s[2 * win] = ss; rec_id[2 * win] = cur; }
                usedL = true;
            } else {
                *(float2*)&out_x[(size_t)cur * 256 + 128 + lane * 2] = make_float2(u0, u1);
                if (lane == 0) Sbuf[cur] = ss;
            }
            u0 = u1 = ss = 0.f;
            cur = bn; a = n;
        }
        float pn = (n < 16) ? __shfl(pt[0], n) : __shfl(pt[1], n - 16);
        unsigned zz = *(const unsigned*)&zb[n][lane * 2];
        u0 += pn * bf2f((unsigned short)(zz & 0xffffu));
        u1 += pn * bf2f((unsigned short)(zz >> 16));
        ss += pn;
    }
    {
        bool lb = (a == 0) && (leftN == cur);
        bool rb = (rightN == cur);
        if (lb) {
            *(float2*)&rec_u[(size_t)(2 * win) * 128 + lane * 2] = make_float2(u0, u1);
            if (lane == 0) { rec_s[2 * win] = ss; rec_id[2 * win] = cur; }
            usedL = true;
        } else if (rb) {
            *(float2*)&rec_u[(size_t)(2 * win + 1) * 128 + lane * 2] = make_float2(u0, u1);
            if (lane == 0) { rec_s[2 * win + 1] = ss; rec_id[2 * win + 1] = cur; }
            usedR = true;
        } else {
            *(float2*)&out_x[(size_t)cur * 256 + 128 + lane * 2] = make_float2(u0, u1);
            if (lane == 0) Sbuf[cur] = ss;
        }
    }
    if (lane == 0) {
        if (!usedL) rec_id[2 * win] = -1;
        if (!usedR) rec_id[2 * win + 1] = -1;
    }
}

// ---------- K4: combine boundary records + normalize + z_mol copy ----------
__global__ __launch_bounds__(256) void combine_kernel(
    const float* __restrict__ z_mol,
    const int*   __restrict__ offs,
    const float* __restrict__ Sbuf,
    const float* __restrict__ rec_u,
    const float* __restrict__ rec_s,
    const int*   __restrict__ rec_id,
    float*       __restrict__ out_x)
{
    const int t = threadIdx.x, lane = t & 63, wv = t >> 6;
    const int g = blockIdx.x * 4 + wv;
    const int gs = offs[g], ge = offs[g + 1];

    float2 U = make_float2(0.f, 0.f);
    float  S = 0.f;
    if (ge > gs) {
        int w0 = gs >> 5, w1 = (ge - 1) >> 5;
        if (w0 == w1) {
            U = *(const float2*)&out_x[(size_t)g * 256 + 128 + lane * 2];
            S = Sbuf[g];
        } else {
            for (int wn = w0; wn <= w1; ++wn) {
                #pragma unroll
                for (int sl = 0; sl < 2; ++sl) {
                    int id = rec_id[2 * wn + sl];
                    if (id == g) {
                        float2 r = *(const float2*)&rec_u[(size_t)(2 * wn + sl) * 128 + lane * 2];
                        U.x += r.x; U.y += r.y;
                        S += rec_s[2 * wn + sl];
                    }
                }
            }
        }
    }
    const float inv = 1.f / (S + 1e-16f);
    float2 zm = *(const float2*)&z_mol[(size_t)g * D_EMB + lane * 2];
    *(float2*)&out_x[(size_t)g * 256 + lane * 2] = zm;
    *(float2*)&out_x[(size_t)g * 256 + 128 + lane * 2] = make_float2(U.x * inv, U.y * inv);
}

// ---------- K5: edge concat ----------
__global__ __launch_bounds__(256) void edge_kernel(
    const float4* __restrict__ edge_attr4,
    const float4* __restrict__ state_emb4,
    const int*    __restrict__ state,
    const int*    __restrict__ eidx,
    const int*    __restrict__ batch,
    float4*       __restrict__ out4,
    int total)
{
    int tid = blockIdx.x * 256 + threadIdx.x;
    if (tid >= total) return;
    int e = tid / 24;
    int q = tid - e * 24;
    float4 v;
    if (q < 8) {
        v = edge_attr4[e * 8 + q];
    } else {
        int n = eidx[e];
        int b = batch[n];
        int s = state[b];
        v = state_emb4[s * 16 + (q - 8)];
    }
    out4[tid] = v;
}

extern "C" void kernel_launch(void* const* d_in, const int* in_sizes, int n_in,
                              void* d_out, int out_size, void* d_ws, size_t ws_size,
                              hipStream_t stream)
{
    const float* edge_attr = (const float*)d_in[0];
    const float* z_mol     = (const float*)d_in[1];
    const float* z_atom    = (const float*)d_in[2];
    const float* state_emb = (const float*)d_in[3];
    const float* W1        = (const float*)d_in[4];
    const float* b1        = (const float*)d_in[5];
    const float* W2        = (const float*)d_in[6];
    const float* b2        = (const float*)d_in[7];
    const int*   state     = (const int*)d_in[8];
    const int*   eidx      = (const int*)d_in[9];
    const int*   batch     = (const int*)d_in[10];

    float* out_x = (float*)d_out;
    float* out_e = out_x + (size_t)B_GRAPHS * 256;

    int*   offs = (int*)d_ws;
    float* hbuf = (float*)((char*)d_ws + 65552);
    float* Sbuf = (float*)((char*)d_ws + 65552 + (size_t)B_GRAPHS * HID * 4);

    float* recbase = out_e + 80000000ull;
    float* rec_u  = recbase;
    float* rec_s  = rec_u + (size_t)NWIN * 2 * 128;
    int*   rec_id = (int*)(rec_s + (size_t)NWIN * 2);

    offs_kernel<<<N_NODES / 256, 256, 0, stream>>>(batch, offs);
    hb_kernel<<<B_GRAPHS / 8, 256, 0, stream>>>(state_emb, W1, b1, state, hbuf);

    window_kernel<<<NWIN / WPB, 256, 0, stream>>>(
        z_atom, W1, W2, b2, batch, hbuf, out_x, Sbuf, rec_u, rec_s, rec_id);

    combine_kernel<<<B_GRAPHS / 4, 256, 0, stream>>>(
        z_mol, offs, Sbuf, rec_u, rec_s, rec_id, out_x);

    // MEASUREMENT: edge_kernel is idempotent (pure function of inputs, writes
    // out4 only) -> launch twice; total-time delta vs R7 = edge duration.
    const int total4 = E_EDGES * 24;
    edge_kernel<<<(total4 + 255) / 256, 256, 0, stream>>>(
        (const float4*)edge_attr, (const float4*)state_emb,
        state, eidx, batch, (float4*)out_e, total4);
    edge_kernel<<<(total4 + 255) / 256, 256, 0, stream>>>(
        (const float4*)edge_attr, (const float4*)state_emb,
        state, eidx, batch, (float4*)out_e, total4);
}

// Round 11
// 187.551 us; speedup vs baseline: 2.2112x; 2.2112x over previous
//
#include <hip/hip_runtime.h>
#include <math.h>

#define B_GRAPHS 16384
#define N_NODES  524288
#define E_EDGES  1048576
#define D_EMB    128
#define D_STATE  64
#define HID      32
#define PADK     136     // bf16 elems/row -> 272B row stride (16B aligned)
#define WPB      4       // waves per block; each wave owns one 32-node window
#define NWIN     (N_NODES / 32)

typedef __attribute__((ext_vector_type(8))) short short8;
typedef __attribute__((ext_vector_type(4))) float f32x4;

__device__ __forceinline__ unsigned short f2bf(float f) {
    unsigned int u = __builtin_bit_cast(unsigned int, f);
    u += 0x7fffu + ((u >> 16) & 1u);
    return (unsigned short)(u >> 16);
}
__device__ __forceinline__ float bf2f(unsigned short s) {
    unsigned int u = ((unsigned int)s) << 16;
    return __builtin_bit_cast(float, u);
}

// ---------- K1: segment offsets (batch sorted) ----------
__global__ __launch_bounds__(256) void offs_kernel(
    const int* __restrict__ batch, int* __restrict__ offs)
{
    int i = blockIdx.x * 256 + threadIdx.x;
    if (i >= N_NODES) return;
    int b = batch[i];
    int prev = (i == 0) ? -1 : batch[i - 1];
    for (int x = prev + 1; x <= b; ++x) offs[x] = i;
    if (i == N_NODES - 1)
        for (int x = b + 1; x <= B_GRAPHS; ++x) offs[x] = N_NODES;
}

// ---------- K2: hb[g][j] = b1[j] + state_emb[state[g]] @ W1[128:192,:] ----------
__global__ __launch_bounds__(256) void hb_kernel(
    const float* __restrict__ state_emb, const float* __restrict__ W1,
    const float* __restrict__ b1, const int* __restrict__ state,
    float* __restrict__ hb)
{
    int t = threadIdx.x;
    int j = t & 31;
    int g = blockIdx.x * 8 + (t >> 5);
    int st = state[g];
    const float* zs = state_emb + st * D_STATE;
    float acc = b1[j];
    #pragma unroll 8
    for (int k = 0; k < D_STATE; ++k)
        acc += zs[k] * W1[(D_EMB + k) * HID + j];
    hb[g * HID + j] = acc;
}

// ---------- K3: window kernel: logits + exp + segment pooling, NO atomics ----------
__global__ __launch_bounds__(256, 3) void window_kernel(
    const float* __restrict__ z_atom,
    const float* __restrict__ W1,
    const float* __restrict__ W2,
    const float* __restrict__ b2,
    const int*   __restrict__ batch,
    const float* __restrict__ hb,
    float*       __restrict__ out_x,
    float*       __restrict__ Sbuf,
    float*       __restrict__ rec_u,   // [NWIN*2][128]
    float*       __restrict__ rec_s,   // [NWIN*2]
    int*         __restrict__ rec_id)  // [NWIN*2]
{
    __shared__ unsigned short s_w1t[HID][PADK];     // W1[0:128,:]^T bf16 [j][k]
    __shared__ unsigned short s_zb[WPB][32][PADK];  // per-wave z window bf16 [n][k]

    const int t    = threadIdx.x;
    const int lane = t & 63;
    const int w    = t >> 6;
    const int l15  = lane & 15;
    const int kc   = lane >> 4;        // 0..3

    for (int i = t; i < D_EMB * HID; i += 256) {
        int k = i >> 5, j = i & 31;
        s_w1t[j][k] = f2bf(W1[i]);
    }
    __syncthreads();

    const float b2v = b2[0];
    float w2v[2][4];
    #pragma unroll
    for (int jh = 0; jh < 2; ++jh)
        #pragma unroll
        for (int r = 0; r < 4; ++r)
            w2v[jh][r] = W2[16 * jh + 4 * kc + r];

    unsigned short (*zb)[PADK] = s_zb[w];

    const int win = blockIdx.x * WPB + w;
    const int c0  = win * 32;
    int bv = 0;
    if (lane < 32) bv = batch[c0 + lane];

    const int leftN  = (c0 > 0) ? batch[c0 - 1] : -2;
    const int rightN = (c0 + 32 < N_NODES) ? batch[c0 + 32] : -2;

    float4 hbf[2][2];
    #pragma unroll
    for (int nh = 0; nh < 2; ++nh) {
        int bn = __shfl(bv, l15 + 16 * nh);
        hbf[nh][0] = *(const float4*)&hb[(size_t)bn * HID + 4 * kc];
        hbf[nh][1] = *(const float4*)&hb[(size_t)bn * HID + 16 + 4 * kc];
    }

    const float4* za4 = (const float4*)z_atom + (size_t)c0 * (D_EMB / 4);
    #pragma unroll
    for (int half = 0; half < 2; ++half) {
        float4 tmp[8];
        #pragma unroll
        for (int it = 0; it < 8; ++it) {
            int idx = (half * 8 + it) * 64 + lane;
            int n = idx >> 5, c = idx & 31;
            tmp[it] = za4[n * (D_EMB / 4) + c];
        }
        #pragma unroll
        for (int it = 0; it < 8; ++it) {
            int idx = (half * 8 + it) * 64 + lane;
            int n = idx >> 5, c = idx & 31;
            float4 v = tmp[it];
            unsigned lo = (unsigned)f2bf(v.x) | ((unsigned)f2bf(v.y) << 16);
            unsigned hi = (unsigned)f2bf(v.z) | ((unsigned)f2bf(v.w) << 16);
            *(uint2*)&zb[n][c * 4] = make_uint2(lo, hi);
        }
    }

    f32x4 acc[2][2] = {{{0.f,0.f,0.f,0.f},{0.f,0.f,0.f,0.f}},
                       {{0.f,0.f,0.f,0.f},{0.f,0.f,0.f,0.f}}};
    #pragma unroll
    for (int kb = 0; kb < 4; ++kb) {
        short8 a0 = *(const short8*)&s_w1t[l15][kb * 32 + kc * 8];
        short8 a1 = *(const short8*)&s_w1t[16 + l15][kb * 32 + kc * 8];
        short8 q0 = *(const short8*)&zb[l15][kb * 32 + kc * 8];
        short8 q1 = *(const short8*)&zb[16 + l15][kb * 32 + kc * 8];
        acc[0][0] = __builtin_amdgcn_mfma_f32_16x16x32_bf16(a0, q0, acc[0][0], 0, 0, 0);
        acc[1][0] = __builtin_amdgcn_mfma_f32_16x16x32_bf16(a1, q0, acc[1][0], 0, 0, 0);
        acc[0][1] = __builtin_amdgcn_mfma_f32_16x16x32_bf16(a0, q1, acc[0][1], 0, 0, 0);
        acc[1][1] = __builtin_amdgcn_mfma_f32_16x16x32_bf16(a1, q1, acc[1][1], 0, 0, 0);
    }

    float pt[2];
    #pragma unroll
    for (int nh = 0; nh < 2; ++nh) {
        float part = 0.f;
        #pragma unroll
        for (int r = 0; r < 4; ++r) {
            float h = acc[0][nh][r] + (&hbf[nh][0].x)[r];
            h = h > 0.f ? h : 0.01f * h;
            part += h * w2v[0][r];
        }
        #pragma unroll
        for (int r = 0; r < 4; ++r) {
            float h = acc[1][nh][r] + (&hbf[nh][1].x)[r];
            h = h > 0.f ? h : 0.01f * h;
            part += h * w2v[1][r];
        }
        part += __shfl_xor(part, 16);
        part += __shfl_xor(part, 32);
        pt[nh] = __expf(part + b2v);
    }

    float u0 = 0.f, u1 = 0.f, ss = 0.f;
    int cur = __shfl(bv, 0);
    int a = 0;
    bool usedL = false, usedR = false;

    #pragma unroll 4
    for (int n = 0; n < 32; ++n) {
        int bn = __shfl(bv, n);
        if (bn != cur) {
            if (a == 0 && leftN == cur) {
                *(float2*)&rec_u[(size_t)(2 * win) * 128 + lane * 2] = make_float2(u0, u1);
                if (lane == 0) { rec_s[2 * win] = ss; rec_id[2 * win] = cur; }
                usedL = true;
            } else {
                *(float2*)&out_x[(size_t)cur * 256 + 128 + lane * 2] = make_float2(u0, u1);
                if (lane == 0) Sbuf[cur] = ss;
            }
            u0 = u1 = ss = 0.f;
            cur = bn; a = n;
        }
        float pn = (n < 16) ? __shfl(pt[0], n) : __shfl(pt[1], n - 16);
        unsigned zz = *(const unsigned*)&zb[n][lane * 2];
        u0 += pn * bf2f((unsigned short)(zz & 0xffffu));
        u1 += pn * bf2f((unsigned short)(zz >> 16));
        ss += pn;
    }
    {
        bool lb = (a == 0) && (leftN == cur);
        bool rb = (rightN == cur);
        if (lb) {
            *(float2*)&rec_u[(size_t)(2 * win) * 128 + lane * 2] = make_float2(u0, u1);
            if (lane == 0) { rec_s[2 * win] = ss; rec_id[2 * win] = cur; }
            usedL = true;
        } else if (rb) {
            *(float2*)&rec_u[(size_t)(2 * win + 1) * 128 + lane * 2] = make_float2(u0, u1);
            if (lane == 0) { rec_s[2 * win + 1] = ss; rec_id[2 * win + 1] = cur; }
            usedR = true;
        } else {
            *(float2*)&out_x[(size_t)cur * 256 + 128 + lane * 2] = make_float2(u0, u1);
            if (lane == 0) Sbuf[cur] = ss;
        }
    }
    if (lane == 0) {
        if (!usedL) rec_id[2 * win] = -1;
        if (!usedR) rec_id[2 * win + 1] = -1;
    }
}

// ---------- K4: combine boundary records + normalize + z_mol copy ----------
__global__ __launch_bounds__(256) void combine_kernel(
    const float* __restrict__ z_mol,
    const int*   __restrict__ offs,
    const float* __restrict__ Sbuf,
    const float* __restrict__ rec_u,
    const float* __restrict__ rec_s,
    const int*   __restrict__ rec_id,
    float*       __restrict__ out_x)
{
    const int t = threadIdx.x, lane = t & 63, wv = t >> 6;
    const int g = blockIdx.x * 4 + wv;
    const int gs = offs[g], ge = offs[g + 1];

    float2 U = make_float2(0.f, 0.f);
    float  S = 0.f;
    if (ge > gs) {
        int w0 = gs >> 5, w1 = (ge - 1) >> 5;
        if (w0 == w1) {
            U = *(const float2*)&out_x[(size_t)g * 256 + 128 + lane * 2];
            S = Sbuf[g];
        } else {
            for (int wn = w0; wn <= w1; ++wn) {
                #pragma unroll
                for (int sl = 0; sl < 2; ++sl) {
                    int id = rec_id[2 * wn + sl];
                    if (id == g) {
                        float2 r = *(const float2*)&rec_u[(size_t)(2 * wn + sl) * 128 + lane * 2];
                        U.x += r.x; U.y += r.y;
                        S += rec_s[2 * wn + sl];
                    }
                }
            }
        }
    }
    const float inv = 1.f / (S + 1e-16f);
    float2 zm = *(const float2*)&z_mol[(size_t)g * D_EMB + lane * 2];
    *(float2*)&out_x[(size_t)g * 256 + lane * 2] = zm;
    *(float2*)&out_x[(size_t)g * 256 + 128 + lane * 2] = make_float2(U.x * inv, U.y * inv);
}

// ---------- K5a: edge attr copy (branch-free stream) ----------
__global__ __launch_bounds__(256) void edge_copy_kernel(
    const f32x4* __restrict__ edge_attr4,
    f32x4*       __restrict__ out4)
{
    int tid = blockIdx.x * 256 + threadIdx.x;    // e*8 + q, q<8
    int e = tid >> 3, q = tid & 7;
    f32x4 v = __builtin_nontemporal_load(&edge_attr4[tid]);
    __builtin_nontemporal_store(v, &out4[(size_t)e * 24 + q]);
}

// ---------- K5b: edge state gather (branch-free) ----------
__global__ __launch_bounds__(256) void edge_state_kernel(
    const f32x4* __restrict__ state_emb4,
    const int*   __restrict__ state,
    const int*   __restrict__ eidx,
    const int*   __restrict__ batch,
    f32x4*       __restrict__ out4)
{
    int tid = blockIdx.x * 256 + threadIdx.x;    // e*16 + q, q<16
    int e = tid >> 4, q = tid & 15;
    int n = eidx[e];                              // 16 lanes share each line
    int b = batch[n];
    int s = state[b];
    f32x4 v = state_emb4[s * 16 + q];             // 2.5 KB table, L1-resident
    __builtin_nontemporal_store(v, &out4[(size_t)e * 24 + 8 + q]);
}

extern "C" void kernel_launch(void* const* d_in, const int* in_sizes, int n_in,
                              void* d_out, int out_size, void* d_ws, size_t ws_size,
                              hipStream_t stream)
{
    const float* edge_attr = (const float*)d_in[0];
    const float* z_mol     = (const float*)d_in[1];
    const float* z_atom    = (const float*)d_in[2];
    const float* state_emb = (const float*)d_in[3];
    const float* W1        = (const float*)d_in[4];
    const float* b1        = (const float*)d_in[5];
    const float* W2        = (const float*)d_in[6];
    const float* b2        = (const float*)d_in[7];
    const int*   state     = (const int*)d_in[8];
    const int*   eidx      = (const int*)d_in[9];
    const int*   batch     = (const int*)d_in[10];

    float* out_x = (float*)d_out;
    float* out_e = out_x + (size_t)B_GRAPHS * 256;

    int*   offs = (int*)d_ws;
    float* hbuf = (float*)((char*)d_ws + 65552);
    float* Sbuf = (float*)((char*)d_ws + 65552 + (size_t)B_GRAPHS * HID * 4);

    float* recbase = out_e + 80000000ull;
    float* rec_u  = recbase;
    float* rec_s  = rec_u + (size_t)NWIN * 2 * 128;
    int*   rec_id = (int*)(rec_s + (size_t)NWIN * 2);

    offs_kernel<<<N_NODES / 256, 256, 0, stream>>>(batch, offs);
    hb_kernel<<<B_GRAPHS / 8, 256, 0, stream>>>(state_emb, W1, b1, state, hbuf);

    window_kernel<<<NWIN / WPB, 256, 0, stream>>>(
        z_atom, W1, W2, b2, batch, hbuf, out_x, Sbuf, rec_u, rec_s, rec_id);

    combine_kernel<<<B_GRAPHS / 4, 256, 0, stream>>>(
        z_mol, offs, Sbuf, rec_u, rec_s, rec_id, out_x);

    edge_copy_kernel<<<(E_EDGES * 8) / 256, 256, 0, stream>>>(
        (const f32x4*)edge_attr, (f32x4*)out_e);
    edge_state_kernel<<<(E_EDGES * 16) / 256, 256, 0, stream>>>(
        (const f32x4*)state_emb, state, eidx, batch, (f32x4*)out_e);
}

// Round 12
// 171.543 us; speedup vs baseline: 2.4175x; 1.0933x over previous
//
#include <hip/hip_runtime.h>
#include <math.h>

#define B_GRAPHS 16384
#define N_NODES  524288
#define E_EDGES  1048576
#define D_EMB    128
#define D_STATE  64
#define HID      32
#define PADK     136     // bf16 elems/row -> 272B row stride (16B aligned)
#define WPB      4       // waves per block; each wave owns one 32-node window
#define NWIN     (N_NODES / 32)

typedef __attribute__((ext_vector_type(8))) short short8;
typedef __attribute__((ext_vector_type(4))) float f32x4;

__device__ __forceinline__ unsigned short f2bf(float f) {
    unsigned int u = __builtin_bit_cast(unsigned int, f);
    u += 0x7fffu + ((u >> 16) & 1u);
    return (unsigned short)(u >> 16);
}
__device__ __forceinline__ float bf2f(unsigned short s) {
    unsigned int u = ((unsigned int)s) << 16;
    return __builtin_bit_cast(float, u);
}

// ---------- K1: prep = offs (blocks 0..2047) + hb (blocks 2048..4095) ----------
__global__ __launch_bounds__(256) void prep_kernel(
    const int*   __restrict__ batch,
    const float* __restrict__ state_emb, const float* __restrict__ W1,
    const float* __restrict__ b1, const int* __restrict__ state,
    int* __restrict__ offs, float* __restrict__ hb)
{
    const int bid = blockIdx.x, t = threadIdx.x;
    if (bid < 2048) {                       // offs part
        int i = bid * 256 + t;
        int b = batch[i];
        int prev = (i == 0) ? -1 : batch[i - 1];
        for (int x = prev + 1; x <= b; ++x) offs[x] = i;
        if (i == N_NODES - 1)
            for (int x = b + 1; x <= B_GRAPHS; ++x) offs[x] = N_NODES;
    } else {                                // hb part
        int j = t & 31;
        int g = (bid - 2048) * 8 + (t >> 5);
        int st = state[g];
        const float* zs = state_emb + st * D_STATE;
        float acc = b1[j];
        #pragma unroll 8
        for (int k = 0; k < D_STATE; ++k)
            acc += zs[k] * W1[(D_EMB + k) * HID + j];
        hb[g * HID + j] = acc;
    }
}

// ---------- K2: window kernel: W1 frags in regs, wave-autonomous, no barrier ----------
__global__ __launch_bounds__(256, 4) void window_kernel(
    const float* __restrict__ z_atom,
    const float* __restrict__ W1,
    const float* __restrict__ W2,
    const float* __restrict__ b2,
    const int*   __restrict__ batch,
    const float* __restrict__ hb,
    float*       __restrict__ out_x,
    float*       __restrict__ Sbuf,
    float*       __restrict__ rec_u,   // [NWIN*2][128]
    float*       __restrict__ rec_s,   // [NWIN*2]
    int*         __restrict__ rec_id)  // [NWIN*2]
{
    __shared__ unsigned short s_zb[WPB][32][PADK];  // per-wave z window bf16 [n][k]

    const int t    = threadIdx.x;
    const int lane = t & 63;
    const int w    = t >> 6;
    const int l15  = lane & 15;
    const int kc   = lane >> 4;        // 0..3

    // W1^T fragments in registers: wa[jh][kb][i] = W1[(kb*32+kc*8+i)*32 + jh*16+l15]
    short8 wa[2][4];
    #pragma unroll
    for (int jh = 0; jh < 2; ++jh)
        #pragma unroll
        for (int kb = 0; kb < 4; ++kb)
            #pragma unroll
            for (int i = 0; i < 8; ++i) {
                int k = kb * 32 + kc * 8 + i;
                wa[jh][kb][i] = (short)f2bf(W1[k * HID + jh * 16 + l15]);
            }

    const float b2v = b2[0];
    float w2v[2][4];
    #pragma unroll
    for (int jh = 0; jh < 2; ++jh)
        #pragma unroll
        for (int r = 0; r < 4; ++r)
            w2v[jh][r] = W2[16 * jh + 4 * kc + r];

    unsigned short (*zb)[PADK] = s_zb[w];

    const int win = blockIdx.x * WPB + w;
    const int c0  = win * 32;
    int bv = 0;
    if (lane < 32) bv = batch[c0 + lane];

    const int leftN  = (c0 > 0) ? batch[c0 - 1] : -2;
    const int rightN = (c0 + 32 < N_NODES) ? batch[c0 + 32] : -2;

    float4 hbf[2][2];
    #pragma unroll
    for (int nh = 0; nh < 2; ++nh) {
        int bn = __shfl(bv, l15 + 16 * nh);
        hbf[nh][0] = *(const float4*)&hb[(size_t)bn * HID + 4 * kc];
        hbf[nh][1] = *(const float4*)&hb[(size_t)bn * HID + 16 + 4 * kc];
    }

    // staging: two batches of 8 f32x4 in registers; nontemporal (read-once stream)
    const f32x4* za4 = (const f32x4*)z_atom + (size_t)c0 * (D_EMB / 4);
    #pragma unroll
    for (int half = 0; half < 2; ++half) {
        f32x4 tmp[8];
        #pragma unroll
        for (int it = 0; it < 8; ++it) {
            int idx = (half * 8 + it) * 64 + lane;
            int n = idx >> 5, c = idx & 31;
            tmp[it] = __builtin_nontemporal_load(&za4[n * (D_EMB / 4) + c]);
        }
        #pragma unroll
        for (int it = 0; it < 8; ++it) {
            int idx = (half * 8 + it) * 64 + lane;
            int n = idx >> 5, c = idx & 31;
            f32x4 v = tmp[it];
            unsigned lo = (unsigned)f2bf(v[0]) | ((unsigned)f2bf(v[1]) << 16);
            unsigned hi = (unsigned)f2bf(v[2]) | ((unsigned)f2bf(v[3]) << 16);
            *(uint2*)&zb[n][c * 4] = make_uint2(lo, hi);
        }
    }

    f32x4 acc[2][2] = {{{0.f,0.f,0.f,0.f},{0.f,0.f,0.f,0.f}},
                       {{0.f,0.f,0.f,0.f},{0.f,0.f,0.f,0.f}}};
    #pragma unroll
    for (int kb = 0; kb < 4; ++kb) {
        short8 q0 = *(const short8*)&zb[l15][kb * 32 + kc * 8];
        short8 q1 = *(const short8*)&zb[16 + l15][kb * 32 + kc * 8];
        acc[0][0] = __builtin_amdgcn_mfma_f32_16x16x32_bf16(wa[0][kb], q0, acc[0][0], 0, 0, 0);
        acc[1][0] = __builtin_amdgcn_mfma_f32_16x16x32_bf16(wa[1][kb], q0, acc[1][0], 0, 0, 0);
        acc[0][1] = __builtin_amdgcn_mfma_f32_16x16x32_bf16(wa[0][kb], q1, acc[0][1], 0, 0, 0);
        acc[1][1] = __builtin_amdgcn_mfma_f32_16x16x32_bf16(wa[1][kb], q1, acc[1][1], 0, 0, 0);
    }

    float pt[2];
    #pragma unroll
    for (int nh = 0; nh < 2; ++nh) {
        float part = 0.f;
        #pragma unroll
        for (int r = 0; r < 4; ++r) {
            float h = acc[0][nh][r] + (&hbf[nh][0].x)[r];
            h = h > 0.f ? h : 0.01f * h;
            part += h * w2v[0][r];
        }
        #pragma unroll
        for (int r = 0; r < 4; ++r) {
            float h = acc[1][nh][r] + (&hbf[nh][1].x)[r];
            h = h > 0.f ? h : 0.01f * h;
            part += h * w2v[1][r];
        }
        part += __shfl_xor(part, 16);
        part += __shfl_xor(part, 32);
        pt[nh] = __expf(part + b2v);
    }

    float u0 = 0.f, u1 = 0.f, ss = 0.f;
    int cur = __shfl(bv, 0);
    int a = 0;
    bool usedL = false, usedR = false;

    #pragma unroll 4
    for (int n = 0; n < 32; ++n) {
        int bn = __shfl(bv, n);
        if (bn != cur) {
            if (a == 0 && leftN == cur) {
                *(float2*)&rec_u[(size_t)(2 * win) * 128 + lane * 2] = make_float2(u0, u1);
                if (lane == 0) { rec_s[2 * win] = ss; rec_id[2 * win] = cur; }
                usedL = true;
            } else {
                *(float2*)&out_x[(size_t)cur * 256 + 128 + lane * 2] = make_float2(u0, u1);
                if (lane == 0) Sbuf[cur] = ss;
            }
            u0 = u1 = ss = 0.f;
            cur = bn; a = n;
        }
        float pn = (n < 16) ? __shfl(pt[0], n) : __shfl(pt[1], n - 16);
        unsigned zz = *(const unsigned*)&zb[n][lane * 2];
        u0 += pn * bf2f((unsigned short)(zz & 0xffffu));
        u1 += pn * bf2f((unsigned short)(zz >> 16));
        ss += pn;
    }
    {
        bool lb = (a == 0) && (leftN == cur);
        bool rb = (rightN == cur);
        if (lb) {
            *(float2*)&rec_u[(size_t)(2 * win) * 128 + lane * 2] = make_float2(u0, u1);
            if (lane == 0) { rec_s[2 * win] = ss; rec_id[2 * win] = cur; }
            usedL = true;
        } else if (rb) {
            *(float2*)&rec_u[(size_t)(2 * win + 1) * 128 + lane * 2] = make_float2(u0, u1);
            if (lane == 0) { rec_s[2 * win + 1] = ss; rec_id[2 * win + 1] = cur; }
            usedR = true;
        } else {
            *(float2*)&out_x[(size_t)cur * 256 + 128 + lane * 2] = make_float2(u0, u1);
            if (lane == 0) Sbuf[cur] = ss;
        }
    }
    if (lane == 0) {
        if (!usedL) rec_id[2 * win] = -1;
        if (!usedR) rec_id[2 * win + 1] = -1;
    }
}

// ---------- K3: combine boundary records + normalize + z_mol copy ----------
__global__ __launch_bounds__(256) void combine_kernel(
    const float* __restrict__ z_mol,
    const int*   __restrict__ offs,
    const float* __restrict__ Sbuf,
    const float* __restrict__ rec_u,
    const float* __restrict__ rec_s,
    const int*   __restrict__ rec_id,
    float*       __restrict__ out_x)
{
    const int t = threadIdx.x, lane = t & 63, wv = t >> 6;
    const int g = blockIdx.x * 4 + wv;
    const int gs = offs[g], ge = offs[g + 1];

    float2 U = make_float2(0.f, 0.f);
    float  S = 0.f;
    if (ge > gs) {
        int w0 = gs >> 5, w1 = (ge - 1) >> 5;
        if (w0 == w1) {
            U = *(const float2*)&out_x[(size_t)g * 256 + 128 + lane * 2];
            S = Sbuf[g];
        } else {
            for (int wn = w0; wn <= w1; ++wn) {
                #pragma unroll
                for (int sl = 0; sl < 2; ++sl) {
                    int id = rec_id[2 * wn + sl];
                    if (id == g) {
                        float2 r = *(const float2*)&rec_u[(size_t)(2 * wn + sl) * 128 + lane * 2];
                        U.x += r.x; U.y += r.y;
                        S += rec_s[2 * wn + sl];
                    }
                }
            }
        }
    }
    const float inv = 1.f / (S + 1e-16f);
    float2 zm = *(const float2*)&z_mol[(size_t)g * D_EMB + lane * 2];
    *(float2*)&out_x[(size_t)g * 256 + lane * 2] = zm;
    *(float2*)&out_x[(size_t)g * 256 + 128 + lane * 2] = make_float2(U.x * inv, U.y * inv);
}

// ---------- K4: edge = copy (blocks < NB_COPY) + state gather (rest) ----------
#define NB_COPY (E_EDGES * 8 / 256)
__global__ __launch_bounds__(256) void edge_kernel(
    const f32x4* __restrict__ edge_attr4,
    const f32x4* __restrict__ state_emb4,
    const int*   __restrict__ state,
    const int*   __restrict__ eidx,
    const int*   __restrict__ batch,
    f32x4*       __restrict__ out4)
{
    const int bid = blockIdx.x, t = threadIdx.x;
    if (bid < NB_COPY) {
        int tid = bid * 256 + t;                  // e*8 + q, q<8
        int e = tid >> 3, q = tid & 7;
        f32x4 v = __builtin_nontemporal_load(&edge_attr4[tid]);
        __builtin_nontemporal_store(v, &out4[(size_t)e * 24 + q]);
    } else {
        int tid = (bid - NB_COPY) * 256 + t;      // e*16 + q, q<16
        int e = tid >> 4, q = tid & 15;
        int n = eidx[e];
        int b = batch[n];
        int s = state[b];
        f32x4 v = state_emb4[s * 16 + q];
        __builtin_nontemporal_store(v, &out4[(size_t)e * 24 + 8 + q]);
    }
}

extern "C" void kernel_launch(void* const* d_in, const int* in_sizes, int n_in,
                              void* d_out, int out_size, void* d_ws, size_t ws_size,
                              hipStream_t stream)
{
    const float* edge_attr = (const float*)d_in[0];
    const float* z_mol     = (const float*)d_in[1];
    const float* z_atom    = (const float*)d_in[2];
    const float* state_emb = (const float*)d_in[3];
    const float* W1        = (const float*)d_in[4];
    const float* b1        = (const float*)d_in[5];
    const float* W2        = (const float*)d_in[6];
    const float* b2        = (const float*)d_in[7];
    const int*   state     = (const int*)d_in[8];
    const int*   eidx      = (const int*)d_in[9];
    const int*   batch     = (const int*)d_in[10];

    float* out_x = (float*)d_out;
    float* out_e = out_x + (size_t)B_GRAPHS * 256;

    int*   offs = (int*)d_ws;
    float* hbuf = (float*)((char*)d_ws + 65552);
    float* Sbuf = (float*)((char*)d_ws + 65552 + (size_t)B_GRAPHS * HID * 4);

    float* recbase = out_e + 80000000ull;
    float* rec_u  = recbase;
    float* rec_s  = rec_u + (size_t)NWIN * 2 * 128;
    int*   rec_id = (int*)(rec_s + (size_t)NWIN * 2);

    prep_kernel<<<4096, 256, 0, stream>>>(batch, state_emb, W1, b1, state, offs, hbuf);

    window_kernel<<<NWIN / WPB, 256, 0, stream>>>(
        z_atom, W1, W2, b2, batch, hbuf, out_x, Sbuf, rec_u, rec_s, rec_id);

    combine_kernel<<<B_GRAPHS / 4, 256, 0, stream>>>(
        z_mol, offs, Sbuf, rec_u, rec_s, rec_id, out_x);

    edge_kernel<<<NB_COPY + (E_EDGES * 16 / 256), 256, 0, stream>>>(
        (const f32x4*)edge_attr, (const f32x4*)state_emb,
        state, eidx, batch, (f32x4*)out_e);
}